// Round 3
// baseline (187.556 us; speedup 1.0000x reference)
//
#include <hip/hip_runtime.h>
#include <hip/hip_fp16.h>

typedef _Float16 f16;
typedef _Float16 f16x8 __attribute__((ext_vector_type(8)));
typedef _Float16 f16x4 __attribute__((ext_vector_type(4)));
typedef float f32x4 __attribute__((ext_vector_type(4)));

#define STR 72  // LDS row stride (f16 elems): 144 B = 9*16B -> b128-aligned, breaks 16-way bank conflict

__device__ __forceinline__ f16x8 relu_add8(f16x8 a, f16x8 b) {
  f16x8 r;
#pragma unroll
  for (int i = 0; i < 8; i++) {
    f16 t = (f16)(a[i] + b[i]);
    r[i] = t > (f16)0 ? t : (f16)0;   // packs to v_pk_add_f16 + v_pk_max_f16
  }
  return r;
}

// ---------------------------------------------------------------------------
// prep: Wt[n][k] = f16(W2[k][n])  (128x1024), Bt[j][c] = f16(x[j]*W1[1][c]) (512x1024)
// ---------------------------------------------------------------------------
__global__ __launch_bounds__(256) void k_prep(const float* __restrict__ x,
                                              const float* __restrict__ W1,
                                              const float* __restrict__ W2,
                                              f16* __restrict__ Wt,
                                              f16* __restrict__ Bt) {
  const int b = blockIdx.x, tid = threadIdx.x;
  if (b < 512) {
    const int t = b * 256 + tid;        // 0..131071, coalesced read of W2
    const int k = t >> 7, n = t & 127;
    Wt[n * 1024 + k] = (f16)W2[t];
  } else {
    const int u = (b - 512) * 256 + tid; // 0..131071 float4-units
    const int j = u >> 8, c4 = (u & 255) << 2;
    const float xj = x[j];
    const float4 wv = *(const float4*)(W1 + 1024 + c4);
    f16x4 o;
    o[0] = (f16)(xj * wv.x); o[1] = (f16)(xj * wv.y);
    o[2] = (f16)(xj * wv.z); o[3] = (f16)(xj * wv.w);
    *(f16x4*)(Bt + j * 1024 + c4) = o;
  }
}

// ---------------------------------------------------------------------------
// fused: per (i, j-tile of 128): h1 -> MFMA h1@W2 -> relu(+b2) -> dot w3 (+b3)
// writes Kmat[i][j] for j >= i (Kmat pre-zeroed)
// ---------------------------------------------------------------------------
__global__ __launch_bounds__(256) void k_fused(
    const float* __restrict__ x, const float* __restrict__ W1,
    const float* __restrict__ b1, const float* __restrict__ b2,
    const float* __restrict__ W3, const float* __restrict__ b3,
    const f16* __restrict__ Wt, const f16* __restrict__ Bt,
    float* __restrict__ Kmat) {
  __shared__ f16 ha[1024];            // f16(x_i*W1[0][c] + b1[c])
  __shared__ f16 a_t[128 * STR];      // h1 chunk [pair(=j local)][k]
  __shared__ f16 b_t[128 * STR];      // W2^T chunk [n][k]

  const int tid = threadIdx.x;
  const int i = blockIdx.y, tj = blockIdx.x;
  if (tj < (i >> 7)) return;          // tile entirely below diagonal
  const int j0 = tj << 7;

  {  // per-WG ha table (1024 c's)
    const float xi = x[i];
    const int c4 = tid << 2;
    const float4 wv = *(const float4*)(W1 + c4);
    const float4 bv = *(const float4*)(b1 + c4);
    f16x4 o;
    o[0] = (f16)fmaf(xi, wv.x, bv.x);
    o[1] = (f16)fmaf(xi, wv.y, bv.y);
    o[2] = (f16)fmaf(xi, wv.z, bv.z);
    o[3] = (f16)fmaf(xi, wv.w, bv.w);
    *(f16x4*)(&ha[c4]) = o;
  }
  __syncthreads();

  const int lane = tid & 63, wv_ = tid >> 6;   // wave id 0..3
  const int cL = lane & 15, q = lane >> 4;     // MFMA lane coords

  f32x4 acc[2][8];
  #pragma unroll
  for (int a = 0; a < 2; a++)
    #pragma unroll
    for (int c = 0; c < 8; c++) acc[a][c] = (f32x4){0.f, 0.f, 0.f, 0.f};

  const int pA = tid >> 1;            // pair row 0..127 for h1 staging
  const int chA = (tid & 1) << 5;     // c offset 0/32
  const f16* btRow = Bt + (j0 + pA) * 1024;

  for (int kc = 0; kc < 1024; kc += 64) {
    // --- stage B: W2^T chunk [128 n][64 k]: 1024 x f16x8 loads -> 4 per thread
    #pragma unroll
    for (int r = 0; r < 4; r++) {
      const int u = tid + (r << 8);
      const int n = u >> 3, o = (u & 7) << 3;
      *(f16x8*)(&b_t[n * STR + o]) = *(const f16x8*)(Wt + n * 1024 + kc + o);
    }
    // --- stage A: h1 = relu(ha + bt), 32 c's per thread (4 groups of 8)
    #pragma unroll
    for (int g = 0; g < 4; g++) {
      const int c = chA + (g << 3);
      const f16x8 bv = *(const f16x8*)(btRow + kc + c);
      const f16x8 hv = *(const f16x8*)(&ha[kc + c]);
      *(f16x8*)(&a_t[pA * STR + c]) = relu_add8(hv, bv);
    }
    __syncthreads();
    // --- MFMA: each wave owns 32 rows x 128 cols
    #pragma unroll
    for (int ks = 0; ks < 2; ks++) {
      const int kk = (ks << 5) + (q << 3);
      const f16x8 a0 = *(const f16x8*)(&a_t[(wv_ * 32 + cL) * STR + kk]);
      const f16x8 a1 = *(const f16x8*)(&a_t[(wv_ * 32 + 16 + cL) * STR + kk]);
      #pragma unroll
      for (int ct = 0; ct < 8; ct++) {
        const f16x8 bf = *(const f16x8*)(&b_t[(ct * 16 + cL) * STR + kk]);
        acc[0][ct] = __builtin_amdgcn_mfma_f32_16x16x32_f16(a0, bf, acc[0][ct], 0, 0, 0);
        acc[1][ct] = __builtin_amdgcn_mfma_f32_16x16x32_f16(a1, bf, acc[1][ct], 0, 0, 0);
      }
    }
    __syncthreads();
  }

  // --- epilogue: out[j] = dot(relu(acc + b2), w3) + b3, store if j >= i
  float b2v[8], w3v[8];
  #pragma unroll
  for (int ct = 0; ct < 8; ct++) {
    b2v[ct] = b2[ct * 16 + cL];
    w3v[ct] = W3[ct * 16 + cL];
  }
  const float b3s = b3[0];
  #pragma unroll
  for (int rt = 0; rt < 2; rt++) {
    #pragma unroll
    for (int r = 0; r < 4; r++) {
      float s = 0.f;
      #pragma unroll
      for (int ct = 0; ct < 8; ct++)
        s = fmaf(fmaxf(acc[rt][ct][r] + b2v[ct], 0.f), w3v[ct], s);
      s += __shfl_xor(s, 1, 64);
      s += __shfl_xor(s, 2, 64);
      s += __shfl_xor(s, 4, 64);
      s += __shfl_xor(s, 8, 64);
      if (cL == 0) {
        const int j = j0 + wv_ * 32 + rt * 16 + q * 4 + r;  // C row = quad*4+reg
        if (j >= i) Kmat[i * 512 + j] = s + b3s;
      }
    }
  }
}

// ---------------------------------------------------------------------------
// atta: C = K^T K, fp32. Symmetry (pb<=qb + mirror) and triangular i-bound
// (K[i][p]==0 for i>p, so i-loop stops at pb+32).
// ---------------------------------------------------------------------------
__global__ __launch_bounds__(256) void k_atta(const float* __restrict__ K,
                                              float* __restrict__ C) {
  const int pb = blockIdx.x * 32, qb = blockIdx.y * 32;
  if (pb > qb) return;
  __shared__ float sp[32][33], sq[32][33];
  const int tid = threadIdx.x;
  const int tx = tid & 15, ty = tid >> 4;
  float c00 = 0.f, c01 = 0.f, c10 = 0.f, c11 = 0.f;
  for (int i0 = 0; i0 < pb + 32; i0 += 32) {
    #pragma unroll
    for (int r = 0; r < 4; r++) {
      const int e = tid + 256 * r, ii = e >> 5, pp = e & 31;
      sp[ii][pp] = K[(i0 + ii) * 512 + pb + pp];
      sq[ii][pp] = K[(i0 + ii) * 512 + qb + pp];
    }
    __syncthreads();
    #pragma unroll 8
    for (int ii = 0; ii < 32; ii++) {
      const float a0 = sp[ii][ty * 2], a1 = sp[ii][ty * 2 + 1];
      const float b0 = sq[ii][tx * 2], b1 = sq[ii][tx * 2 + 1];
      c00 = fmaf(a0, b0, c00); c01 = fmaf(a0, b1, c01);
      c10 = fmaf(a1, b0, c10); c11 = fmaf(a1, b1, c11);
    }
    __syncthreads();
  }
  const int p0 = pb + ty * 2, q0 = qb + tx * 2;
  C[p0 * 512 + q0] = c00;       C[p0 * 512 + q0 + 1] = c01;
  C[(p0 + 1) * 512 + q0] = c10; C[(p0 + 1) * 512 + q0 + 1] = c11;
  // mirror (symmetric); diagonal blocks rewrite identical values — benign
  C[q0 * 512 + p0] = c00;       C[(q0 + 1) * 512 + p0] = c01;
  C[q0 * 512 + p0 + 1] = c10;   C[(q0 + 1) * 512 + p0 + 1] = c11;
}

extern "C" void kernel_launch(void* const* d_in, const int* in_sizes, int n_in,
                              void* d_out, int out_size, void* d_ws, size_t ws_size,
                              hipStream_t stream) {
  const float* x  = (const float*)d_in[0];
  const float* W1 = (const float*)d_in[1];
  const float* b1 = (const float*)d_in[2];
  const float* W2 = (const float*)d_in[3];
  const float* b2 = (const float*)d_in[4];
  const float* W3 = (const float*)d_in[5];
  const float* b3 = (const float*)d_in[6];
  float* out = (float*)d_out;
  char* ws = (char*)d_ws;

  f16* Wt    = (f16*)ws;                                    // 256 KB: W2^T f16
  f16* Bt    = (f16*)(ws + (256 << 10));                    // 1 MB:  x[j]*W1[1][:] f16
  float* Kmat = (float*)(ws + (256 << 10) + (1 << 20));     // 1 MB:  triu(out)

  (void)hipMemsetAsync(Kmat, 0, 512 * 512 * sizeof(float), stream);
  k_prep<<<1024, 256, 0, stream>>>(x, W1, W2, Wt, Bt);
  k_fused<<<dim3(4, 512), 256, 0, stream>>>(x, W1, b1, b2, W3, b3, Wt, Bt, Kmat);
  k_atta<<<dim3(16, 16), 256, 0, stream>>>(Kmat, out);
}